// Round 9
// baseline (298.630 us; speedup 1.0000x reference)
//
#include <hip/hip_runtime.h>

// MFMA f16 conv pipeline, round 9.
// Round-8 post-mortem: conv1 balanced-but-idle (Mfma 14/VALU 31/HBM 24);
// biggest VALU consumer = shuffle-transpose staging (~150 inst/thread-iter).
// b128 LDS conflicts act within 8-lane phase groups: conv1 PADB=48 clean,
// conv2 PADB=64 = 4-way on every B read. Fixes: (1) conv1 staging via
// 4x scalar-dword channel gather + cvt pack + ds_write_b64 (no shuffles);
// (2) conv2 PADB 64->80; (3) unroll sh-loop (compile-time offsets).
//
// Layouts (CDNA4):
//   16x16x32: A/B k=(lane>>4)*8+j, m/n=lane&15; D col=lane&15, row=(lane>>4)*4+reg
//   32x32x16: A/B k=(lane>>5)*8+j, m/n=lane&31; D col=lane&31,
//             row=(reg&3)+8*(reg>>2)+4*(lane>>5)

typedef _Float16 f16;
typedef _Float16 f16x8 __attribute__((ext_vector_type(8)));
typedef _Float16 f16x4 __attribute__((ext_vector_type(4)));
typedef float f32x4 __attribute__((ext_vector_type(4)));
typedef float f32x16 __attribute__((ext_vector_type(16)));

// ---------------- weight pre-pack ----------------
// frags (1024B = [lane][j] f16): conv1: 9 (32x32 A, ks=kh*3+kw); conv2: 36 @9;
// conv3: 72 @45; conv4: 72 @117. Total 189.
__global__ __launch_bounds__(512)
void pack_weights(const float* __restrict__ w1, const float* __restrict__ w2,
                  const float* __restrict__ w3, const float* __restrict__ w4,
                  f16* __restrict__ apack) {
  int idx = blockIdx.x * 512 + threadIdx.x;   // 189*512 total
  int frag = idx >> 9;
  int e = idx & 511;
  int lane = e >> 3, j = e & 7;
  float v = 0.f;
  if (frag < 9) {
    int kh = frag / 3, kw = frag % 3;
    int oc = lane & 31;
    int ic = (lane >> 5) * 8 + j;
    if (ic < 12) v = w1[((oc * 12 + ic) * 3 + kh) * 3 + kw];
  } else if (frag < 45) {
    int f = frag - 9;
    int sh = f >> 2, og = f & 3;
    int kh = sh / 3, kw = sh % 3;
    int row16 = lane & 15, kg = lane >> 4;
    int oc = og * 16 + row16;
    int ic = kg * 8 + j;
    v = w2[((oc * 32 + ic) * 3 + kh) * 3 + kw];
  } else {
    const float* w = (frag < 117) ? w3 : w4;
    int f = frag - ((frag < 117) ? 45 : 117);
    int sk = f >> 2, og = f & 3;
    int sh = sk >> 1, ks = sk & 1;
    int kh = sh / 3, kw = sh % 3;
    int row16 = lane & 15, kg = lane >> 4;
    int oc = og * 16 + row16;
    int ic = ks * 32 + kg * 8 + j;
    v = w[((oc * 64 + ic) * 3 + kh) * 3 + kw];
  }
  apack[idx] = (f16)v;
}

// ---------------- conv1: 12ch fp32 NCHW -> 32ch NHWC f16, pool ----------------
// Block: 4 conv rows x 128 px, 512 threads (8 waves; wave: 2 conv rows x 32 px,
// 32x32x16 MFMA, k=144 = 9 (kh,kw) x 16ic). Staging: thread = (px, 4-channel
// group); 4 coalesced scalar loads -> f16x4 -> one ds_write_b64. No shuffles.
__global__ __launch_bounds__(512)
void conv1_mfma(const float* __restrict__ x, const f16* __restrict__ apack,
                const float* __restrict__ bias, f16* __restrict__ hout) {
  constexpr int W = 128, H = 128;
  constexpr int SR = 6, PADB = 48, ROWB = 130 * PADB;  // 6240 B/row-slot
  __shared__ char smem[SR * ROWB];                     // 37440 B -> 4 blk/CU
  const int tid = threadIdx.x;
  const int n = blockIdx.y;
  const int r0 = blockIdx.x * 4;

  // zero halo columns (px 0 and 129)
  if (tid < 36) {
    int slot = tid / 6, r = tid % 6;
    int px = (r >= 3) ? 129 : 0;
    int ch = r % 3;
    *(float4*)(smem + slot * ROWB + px * PADB + ch * 16) =
        make_float4(0.f, 0.f, 0.f, 0.f);
  }
  // staging: thread -> px = tid&127, cg = tid>>7 (channels 4cg..4cg+3).
  // cg 0..2 gather-load; cg 3 writes the ic 12..15 zero pad.
  {
    const int px = tid & 127;
    const int cg = tid >> 7;
    if (cg < 3) {
      float v[SR][4];
#pragma unroll
      for (int sr = 0; sr < SR; ++sr) {       // phase 1: issue all loads
        const int ri = r0 + sr - 1;
        const bool ok = (ri >= 0 && ri < H);
        const float* base = x + ((size_t)(n * 12 + cg * 4) * H + (ok ? ri : 0)) * W + px;
#pragma unroll
        for (int c = 0; c < 4; ++c)
          v[sr][c] = ok ? base[(size_t)c * H * W] : 0.f;
      }
#pragma unroll
      for (int sr = 0; sr < SR; ++sr) {       // phase 2: cvt + write
        f16x4 h = { (f16)v[sr][0], (f16)v[sr][1], (f16)v[sr][2], (f16)v[sr][3] };
        *(f16x4*)(smem + sr * ROWB + (px + 1) * PADB + cg * 8) = h;
      }
    } else {
      f16x4 z = {};
#pragma unroll
      for (int sr = 0; sr < SR; ++sr)
        *(f16x4*)(smem + sr * ROWB + (px + 1) * PADB + 24) = z;
    }
  }
  __syncthreads();

  const int wv = tid >> 6, l = tid & 63;
  const int rp = wv >> 2;                // pooled row within block (0..1)
  const int pxb = (wv & 3) * 32;
  const int rl0 = rp * 2;
  const int ln = l & 31;                 // px lane (n of MFMA)
  const int hi = l >> 5;                 // k-half / D row offset

  f16x8 A[9];
#pragma unroll
  for (int ks = 0; ks < 9; ++ks)
    A[ks] = *(const f16x8*)(apack + ((ks << 9) + (l << 3)));

  f32x16 acc[2];
  acc[0] = (f32x16)0.f;
  acc[1] = (f32x16)0.f;

#pragma unroll
  for (int rowi = 0; rowi < 2; ++rowi) {
#pragma unroll
    for (int ks = 0; ks < 9; ++ks) {
      const int kh = ks / 3, kw = ks % 3;
      const int slot = rl0 + rowi + kh;          // <= 5
      f16x8 B = *(const f16x8*)(smem + slot * ROWB + (pxb + ln + kw) * PADB + hi * 16);
      acc[rowi] = __builtin_amdgcn_mfma_f32_32x32x16_f16(A[ks], B, acc[rowi], 0, 0, 0);
    }
  }
  // epilogue: pool 2x2, bias, relu, NHWC f16 store (OC=32)
  // D: px = ln, oc = (reg&3) + 8*(reg>>2) + 4*hi
  const int pr = blockIdx.x * 2 + rp;
#pragma unroll
  for (int g = 0; g < 4; ++g) {
    float v[4];
#pragma unroll
    for (int c = 0; c < 4; ++c) {
      float m = fmaxf(acc[0][g * 4 + c], acc[1][g * 4 + c]);
      v[c] = fmaxf(m, __shfl_xor(m, 1));
    }
    if ((l & 1) == 0) {
      const int pw = (pxb + ln) >> 1;
      const int oc0 = g * 8 + hi * 4;
      f16x4 pk;
#pragma unroll
      for (int c = 0; c < 4; ++c)
        pk[c] = (f16)fmaxf(v[c] + bias[oc0 + c], 0.f);
      *(f16x4*)(hout + (((size_t)(n * 64 + pr) * 64 + pw) * 32 + oc0)) = pk;
    }
  }
}

// ---------------- conv2/3/4: NHWC f16 -> NHWC f16 (or NCHW f32), pool ----------
template<int C, int W, int H, int BR, int KS, int PADB, int PGn, bool NCHW_OUT>
__global__ __launch_bounds__(256)
void conv_shift(const f16* __restrict__ hin, const f16* __restrict__ apack,
                const float* __restrict__ bias, void* __restrict__ hout) {
  constexpr int SR = BR + 2;
  constexpr int ROWB = (W + 2) * PADB;
  __shared__ char smem[SR * ROWB];
  const int tid = threadIdx.x;
  const int n = blockIdx.y;
  const int r0 = blockIdx.x * BR;
  constexpr int CPC = C / 8;
  constexpr int TOTC = SR * (W + 2) * CPC;
  constexpr int NITER = (TOTC + 255) / 256;
  {
    float4 stg[NITER];
#pragma unroll
    for (int it = 0; it < NITER; ++it) {     // phase 1: issue all loads
      const int t = tid + it * 256;
      float4 v = make_float4(0.f, 0.f, 0.f, 0.f);
      if (t < TOTC) {
        int sr = t / ((W + 2) * CPC);
        int rem = t - sr * ((W + 2) * CPC);
        int px = rem / CPC;
        int kc = rem - px * CPC;
        int ri = r0 + sr - 1;
        int gx = px - 1;
        if (ri >= 0 && ri < H && gx >= 0 && gx < W)
          v = *(const float4*)(hin + (((size_t)(n * H + ri) * W + gx) * C + kc * 8));
      }
      stg[it] = v;
    }
#pragma unroll
    for (int it = 0; it < NITER; ++it) {     // phase 2: write to LDS
      const int t = tid + it * 256;
      if (t < TOTC) {
        int sr = t / ((W + 2) * CPC);
        int rem = t - sr * ((W + 2) * CPC);
        int px = rem / CPC;
        int kc = rem - px * CPC;
        *(float4*)(smem + sr * ROWB + px * PADB + kc * 16) = stg[it];
      }
    }
  }
  __syncthreads();

  const int wv = tid >> 6, l = tid & 63;
  constexpr int WPP = W / (16 * PGn);
  const int rp = wv / WPP;
  const int pxb = (wv % WPP) * 16 * PGn;
  const int rl0 = rp * 2;
  const int lp = l & 15, kg = l >> 4;
  const int px0 = pxb + lp;

  f32x4 acc[2][PGn][4];
#pragma unroll
  for (int a = 0; a < 2; ++a)
#pragma unroll
    for (int b = 0; b < PGn; ++b)
#pragma unroll
      for (int c = 0; c < 4; ++c)
        acc[a][b][c] = (f32x4){0.f, 0.f, 0.f, 0.f};

#pragma unroll
  for (int sh = 0; sh < 9; ++sh) {
    const int kh = sh / 3, kw = sh % 3;
    f16x8 A[KS][4];
#pragma unroll
    for (int ks = 0; ks < KS; ++ks)
#pragma unroll
      for (int og = 0; og < 4; ++og)
        A[ks][og] = *(const f16x8*)(apack + ((((sh * KS + ks) * 4 + og) << 9) + (l << 3)));
#pragma unroll
    for (int rowi = 0; rowi < 2; ++rowi) {
      const char* base = smem + (rl0 + rowi + kh) * ROWB;
#pragma unroll
      for (int pg = 0; pg < PGn; ++pg) {
#pragma unroll
        for (int ks = 0; ks < KS; ++ks) {
          f16x8 B = *(const f16x8*)(base + (px0 + pg * 16 + kw) * PADB + ks * 64 + kg * 16);
#pragma unroll
          for (int og = 0; og < 4; ++og)
            acc[rowi][pg][og] =
                __builtin_amdgcn_mfma_f32_16x16x32_f16(A[ks][og], B, acc[rowi][pg][og], 0, 0, 0);
        }
      }
    }
  }
  constexpr int PH = H / 2, PW = W / 2;
  const int pr = blockIdx.x * (BR / 2) + rp;
#pragma unroll
  for (int pg = 0; pg < PGn; ++pg) {
#pragma unroll
    for (int og = 0; og < 4; ++og) {
      float v[4];
#pragma unroll
      for (int c = 0; c < 4; ++c) {
        float m = fmaxf(acc[0][pg][og][c], acc[1][pg][og][c]);
        v[c] = fmaxf(m, __shfl_xor(m, 1));
      }
      if ((l & 1) == 0) {
        const int pw = (pxb + pg * 16 + lp) >> 1;
        const int oc0 = og * 16 + kg * 4;
        if constexpr (NCHW_OUT) {
          float* o = (float*)hout;
#pragma unroll
          for (int c = 0; c < 4; ++c)
            o[(((size_t)n * 64 + oc0 + c) * PH + pr) * PW + pw] =
                fmaxf(v[c] + bias[oc0 + c], 0.f);
        } else {
          f16x4 pk;
#pragma unroll
          for (int c = 0; c < 4; ++c)
            pk[c] = (f16)fmaxf(v[c] + bias[oc0 + c], 0.f);
          *(f16x4*)((f16*)hout + (((size_t)(n * PH + pr) * PW + pw) * 64 + oc0)) = pk;
        }
      }
    }
  }
}

// ---------------- FC head: 2 batch rows/block, 8-way K-split, 1024 thr --------
// scan collapses: fx = h.(wl2[0]+20*wl2[2]) + bl2[0]+20*bl2[2]
__global__ __launch_bounds__(1024)
void fc_head(const float* __restrict__ h4, const float* __restrict__ wl1,
             const float* __restrict__ bl1, const float* __restrict__ wl2,
             const float* __restrict__ bl2, float* __restrict__ out) {
  __shared__ float rows[2][4096];
  __shared__ float red[8 * 128 * 2];
  __shared__ float red2[2 * 128];
  const int tid = threadIdx.x;
  const int b0 = blockIdx.x * 2;
  {
    const float4* src = (const float4*)(h4 + (size_t)b0 * 4096);
    float4* dst = (float4*)rows;
    for (int t = tid; t < 2048; t += 1024) dst[t] = src[t];
  }
  __syncthreads();

  const int nn = tid & 127;
  const int ks = tid >> 7;                 // 0..7, 512 K each
  const float4* wp = (const float4*)(wl1 + (size_t)nn * 4096 + ks * 512);
  const float4* x0 = (const float4*)(&rows[0][ks * 512]);
  const float4* x1 = (const float4*)(&rows[1][ks * 512]);
  float s0 = 0.f, s1 = 0.f;
#pragma unroll 8
  for (int i = 0; i < 128; ++i) {
    float4 w = wp[i], a = x0[i], b = x1[i];
    s0 = fmaf(w.x, a.x, fmaf(w.y, a.y, fmaf(w.z, a.z, fmaf(w.w, a.w, s0))));
    s1 = fmaf(w.x, b.x, fmaf(w.y, b.y, fmaf(w.z, b.z, fmaf(w.w, b.w, s1))));
  }
  red[(ks * 128 + nn) * 2 + 0] = s0;
  red[(ks * 128 + nn) * 2 + 1] = s1;
  __syncthreads();

  if (tid < 256) {
    const int r = tid >> 7, n2 = tid & 127;
    float h = bl1[n2];
#pragma unroll
    for (int k = 0; k < 8; ++k) h += red[(k * 128 + n2) * 2 + r];
    h = fmaxf(h, 0.f);
    red2[r * 128 + n2] = h * (wl2[n2] + 20.0f * wl2[256 + n2]);
  }
  __syncthreads();
#pragma unroll
  for (int s = 64; s > 0; s >>= 1) {
    if (tid < 2 * s) {
      int r = tid / s, i = tid - r * s;
      red2[r * 128 + i] += red2[r * 128 + i + s];
    }
    __syncthreads();
  }
  if (tid < 2) out[b0 + tid] = red2[tid * 128] + bl2[0] + 20.0f * bl2[2];
}

extern "C" void kernel_launch(void* const* d_in, const int* in_sizes, int n_in,
                              void* d_out, int out_size, void* d_ws, size_t ws_size,
                              hipStream_t stream) {
  const float* x   = (const float*)d_in[0];
  const float* w1  = (const float*)d_in[1];
  const float* b1  = (const float*)d_in[2];
  const float* w2  = (const float*)d_in[3];
  const float* b2  = (const float*)d_in[4];
  const float* w3  = (const float*)d_in[5];
  const float* b3  = (const float*)d_in[6];
  const float* w4  = (const float*)d_in[7];
  const float* b4  = (const float*)d_in[8];
  const float* wl1 = (const float*)d_in[9];
  const float* bl1 = (const float*)d_in[10];
  const float* wl2 = (const float*)d_in[11];
  const float* bl2 = (const float*)d_in[12];
  float* out = (float*)d_out;
  char* ws = (char*)d_ws;

  f16* apack = (f16*)ws;
  f16* h1 = (f16*)(ws + (1u << 20));
  f16* h2 = (f16*)(ws + 68157440u);
  f16* h3 = (f16*)(ws + 101711872u);
  float* h4 = (float*)(ws + 110100480u);

  pack_weights<<<189, 512, 0, stream>>>(w1, w2, w3, w4, apack);
  conv1_mfma<<<dim3(32, 256), 512, 0, stream>>>(x, apack, b1, h1);
  conv_shift<32, 64, 64, 4, 1, 80, 2, false><<<dim3(16, 256), 256, 0, stream>>>(
      h1, apack + 9 * 512, b2, (void*)h2);
  conv_shift<64, 32, 32, 8, 2, 144, 2, false><<<dim3(4, 256), 256, 0, stream>>>(
      h2, apack + 45 * 512, b3, (void*)h3);
  conv_shift<64, 16, 16, 8, 2, 144, 1, true><<<dim3(2, 256), 256, 0, stream>>>(
      h3, apack + 117 * 512, b4, (void*)h4);
  fc_head<<<128, 1024, 0, stream>>>(h4, wl1, bl1, wl2, bl2, out);
}

// Round 10
// 246.302 us; speedup vs baseline: 1.2125x; 1.2125x over previous
//
#include <hip/hip_runtime.h>

// MFMA f16 conv pipeline, round 10.
// Round-9 post-mortem: scalar-gather staging regressed conv1 (VGPR crushed to
// 32 -> loads serialized; 183us). Revert to round-8 shuffle-transpose staging
// (proven 115us) and add the structural fix: TPB=8 tiles/block with
// double-buffered LDS; loads for tile t+1 issue before compute(t) so HBM
// latency hides under MFMA+LDS. conv2-4 keep round-9 wins (PADB=80, unroll).
//
// Layouts (CDNA4):
//   16x16x32: A/B k=(lane>>4)*8+j, m/n=lane&15; D col=lane&15, row=(lane>>4)*4+reg
//   32x32x16: A/B k=(lane>>5)*8+j, m/n=lane&31; D col=lane&31,
//             row=(reg&3)+8*(reg>>2)+4*(lane>>5)

typedef _Float16 f16;
typedef _Float16 f16x8 __attribute__((ext_vector_type(8)));
typedef _Float16 f16x4 __attribute__((ext_vector_type(4)));
typedef float f32x4 __attribute__((ext_vector_type(4)));
typedef float f32x16 __attribute__((ext_vector_type(16)));

// ---------------- weight pre-pack ----------------
// frags (1024B = [lane][j] f16): conv1: 9 (32x32 A, ks=kh*3+kw); conv2: 36 @9;
// conv3: 72 @45; conv4: 72 @117. Total 189.
__global__ __launch_bounds__(512)
void pack_weights(const float* __restrict__ w1, const float* __restrict__ w2,
                  const float* __restrict__ w3, const float* __restrict__ w4,
                  f16* __restrict__ apack) {
  int idx = blockIdx.x * 512 + threadIdx.x;   // 189*512 total
  int frag = idx >> 9;
  int e = idx & 511;
  int lane = e >> 3, j = e & 7;
  float v = 0.f;
  if (frag < 9) {
    int kh = frag / 3, kw = frag % 3;
    int oc = lane & 31;
    int ic = (lane >> 5) * 8 + j;
    if (ic < 12) v = w1[((oc * 12 + ic) * 3 + kh) * 3 + kw];
  } else if (frag < 45) {
    int f = frag - 9;
    int sh = f >> 2, og = f & 3;
    int kh = sh / 3, kw = sh % 3;
    int row16 = lane & 15, kg = lane >> 4;
    int oc = og * 16 + row16;
    int ic = kg * 8 + j;
    v = w2[((oc * 32 + ic) * 3 + kh) * 3 + kw];
  } else {
    const float* w = (frag < 117) ? w3 : w4;
    int f = frag - ((frag < 117) ? 45 : 117);
    int sk = f >> 2, og = f & 3;
    int sh = sk >> 1, ks = sk & 1;
    int kh = sh / 3, kw = sh % 3;
    int row16 = lane & 15, kg = lane >> 4;
    int oc = og * 16 + row16;
    int ic = ks * 32 + kg * 8 + j;
    v = w[((oc * 64 + ic) * 3 + kh) * 3 + kw];
  }
  apack[idx] = (f16)v;
}

// ---------------- conv1: 12ch fp32 NCHW -> 32ch NHWC f16, pool ----------------
// Block: TPB=8 tiles of (4 conv rows x 128 px), 512 threads, dbuf LDS.
// Per tile: wave = 2 conv rows x 32 px, 32x32x16 MFMA, k=144 = 9 (kh,kw) x 16ic.
// Staging = round-8 shuffle transpose (float4 loads, conflict-free b64 writes).
__global__ __launch_bounds__(512, 4)
void conv1_mfma(const float* __restrict__ x, const f16* __restrict__ apack,
                const float* __restrict__ bias, f16* __restrict__ hout) {
  constexpr int W = 128, H = 128;
  constexpr int SR = 6, PADB = 48, ROWB = 130 * PADB;  // 6240 B/row-slot
  constexpr int TPB = 8;
  __shared__ char smem[2][SR * ROWB];                  // 74880 B -> 2 blk/CU
  const int tid = threadIdx.x;
  const int n = blockIdx.y;

  // zero halo columns (px 0 and 129) of BOTH buffers (never rewritten)
  if (tid < 72) {
    int b = tid / 36, rem = tid % 36;
    int slot = rem / 6, r = rem % 6;
    int px = (r >= 3) ? 129 : 0;
    int ch = r % 3;
    *(float4*)(smem[b] + slot * ROWB + px * PADB + ch * 16) =
        make_float4(0.f, 0.f, 0.f, 0.f);
  }

  // staging roles: group g (=tid>>4) owns px chunk g (4 px) for all 6 slots.
  const int g = tid >> 4;
  const int l16 = tid & 15;
  const int Q = l16 >> 2, q = l16 & 3;       // quad, lane-in-quad
  float4 a[SR];

  auto load_tile = [&](int t) {
    const int r0 = (blockIdx.x * TPB + t) * 4;
#pragma unroll
    for (int sr = 0; sr < SR; ++sr) {        // all loads independent/pipelined
      const int ri = r0 + sr - 1;
      a[sr] = make_float4(0.f, 0.f, 0.f, 0.f);
      if (l16 < 12 && ri >= 0 && ri < H)
        a[sr] = *(const float4*)(x + ((size_t)(n * 12 + l16) * H + ri) * W + g * 4);
    }
  };
  auto write_tile = [&](char* buf) {
#pragma unroll
    for (int sr = 0; sr < SR; ++sr) {        // 4x4 quad transpose + b64 write
      float4 t1, t2;
      {
        float sx = __shfl_xor(a[sr].x, 1), sy = __shfl_xor(a[sr].y, 1);
        float sz = __shfl_xor(a[sr].z, 1), sw = __shfl_xor(a[sr].w, 1);
        bool odd = q & 1;
        t1.x = odd ? sy : a[sr].x;  t1.y = odd ? a[sr].y : sx;
        t1.z = odd ? sw : a[sr].z;  t1.w = odd ? a[sr].w : sz;
      }
      {
        float sx = __shfl_xor(t1.x, 2), sy = __shfl_xor(t1.y, 2);
        float sz = __shfl_xor(t1.z, 2), sw = __shfl_xor(t1.w, 2);
        bool hi2 = q & 2;
        t2.x = hi2 ? sz : t1.x;  t2.y = hi2 ? sw : t1.y;
        t2.z = hi2 ? t1.z : sx;  t2.w = hi2 ? t1.w : sy;
      }
      f16x4 h = { (f16)t2.x, (f16)t2.y, (f16)t2.z, (f16)t2.w };
      *(f16x4*)(buf + sr * ROWB + (g * 4 + q + 1) * PADB + Q * 8) = h;
    }
  };

  // compute-role indices
  const int wv = tid >> 6, l = tid & 63;
  const int rp = wv >> 2;                // pooled row within tile (0..1)
  const int pxb = (wv & 3) * 32;
  const int rl0 = rp * 2;
  const int ln = l & 31;                 // px lane (n of MFMA)
  const int hi = l >> 5;                 // k-half / D row offset

  f16x8 A[9];
#pragma unroll
  for (int ks = 0; ks < 9; ++ks)
    A[ks] = *(const f16x8*)(apack + ((ks << 9) + (l << 3)));

  auto compute = [&](const char* buf, int tg) {
    f32x16 acc0 = (f32x16)0.f, acc1 = (f32x16)0.f;
#pragma unroll
    for (int ks = 0; ks < 9; ++ks) {
      const int kh = ks / 3, kw = ks % 3;
      const char* base = buf + (pxb + ln + kw) * PADB + hi * 16;
      f16x8 B0 = *(const f16x8*)(base + (rl0 + kh) * ROWB);
      acc0 = __builtin_amdgcn_mfma_f32_32x32x16_f16(A[ks], B0, acc0, 0, 0, 0);
      f16x8 B1 = *(const f16x8*)(base + (rl0 + 1 + kh) * ROWB);
      acc1 = __builtin_amdgcn_mfma_f32_32x32x16_f16(A[ks], B1, acc1, 0, 0, 0);
    }
    // epilogue: pool 2x2, bias, relu, NHWC f16 store (OC=32)
    const int pr = tg * 2 + rp;
#pragma unroll
    for (int gg = 0; gg < 4; ++gg) {
      float v[4];
#pragma unroll
      for (int c = 0; c < 4; ++c) {
        float m = fmaxf(acc0[gg * 4 + c], acc1[gg * 4 + c]);
        v[c] = fmaxf(m, __shfl_xor(m, 1));
      }
      if ((l & 1) == 0) {
        const int pw = (pxb + ln) >> 1;
        const int oc0 = gg * 8 + hi * 4;
        f16x4 pk;
#pragma unroll
        for (int c = 0; c < 4; ++c)
          pk[c] = (f16)fmaxf(v[c] + bias[oc0 + c], 0.f);
        *(f16x4*)(hout + (((size_t)(n * 64 + pr) * 64 + pw) * 32 + oc0)) = pk;
      }
    }
  };

  // prologue: tile 0 staged serially
  load_tile(0);
  write_tile(smem[0]);
  __syncthreads();

  for (int t = 0; t < TPB; ++t) {
    if (t + 1 < TPB) load_tile(t + 1);           // issue early: hides under compute
    compute(smem[t & 1], blockIdx.x * TPB + t);
    __syncthreads();
    if (t + 1 < TPB) {
      write_tile(smem[(t + 1) & 1]);             // buffer free: last read at t-1
      __syncthreads();
    }
  }
}

// ---------------- conv2/3/4: NHWC f16 -> NHWC f16 (or NCHW f32), pool ----------
template<int C, int W, int H, int BR, int KS, int PADB, int PGn, bool NCHW_OUT>
__global__ __launch_bounds__(256)
void conv_shift(const f16* __restrict__ hin, const f16* __restrict__ apack,
                const float* __restrict__ bias, void* __restrict__ hout) {
  constexpr int SR = BR + 2;
  constexpr int ROWB = (W + 2) * PADB;
  __shared__ char smem[SR * ROWB];
  const int tid = threadIdx.x;
  const int n = blockIdx.y;
  const int r0 = blockIdx.x * BR;
  constexpr int CPC = C / 8;
  constexpr int TOTC = SR * (W + 2) * CPC;
  constexpr int NITER = (TOTC + 255) / 256;
  {
    float4 stg[NITER];
#pragma unroll
    for (int it = 0; it < NITER; ++it) {     // phase 1: issue all loads
      const int t = tid + it * 256;
      float4 v = make_float4(0.f, 0.f, 0.f, 0.f);
      if (t < TOTC) {
        int sr = t / ((W + 2) * CPC);
        int rem = t - sr * ((W + 2) * CPC);
        int px = rem / CPC;
        int kc = rem - px * CPC;
        int ri = r0 + sr - 1;
        int gx = px - 1;
        if (ri >= 0 && ri < H && gx >= 0 && gx < W)
          v = *(const float4*)(hin + (((size_t)(n * H + ri) * W + gx) * C + kc * 8));
      }
      stg[it] = v;
    }
#pragma unroll
    for (int it = 0; it < NITER; ++it) {     // phase 2: write to LDS
      const int t = tid + it * 256;
      if (t < TOTC) {
        int sr = t / ((W + 2) * CPC);
        int rem = t - sr * ((W + 2) * CPC);
        int px = rem / CPC;
        int kc = rem - px * CPC;
        *(float4*)(smem + sr * ROWB + px * PADB + kc * 16) = stg[it];
      }
    }
  }
  __syncthreads();

  const int wv = tid >> 6, l = tid & 63;
  constexpr int WPP = W / (16 * PGn);
  const int rp = wv / WPP;
  const int pxb = (wv % WPP) * 16 * PGn;
  const int rl0 = rp * 2;
  const int lp = l & 15, kg = l >> 4;
  const int px0 = pxb + lp;

  f32x4 acc[2][PGn][4];
#pragma unroll
  for (int a = 0; a < 2; ++a)
#pragma unroll
    for (int b = 0; b < PGn; ++b)
#pragma unroll
      for (int c = 0; c < 4; ++c)
        acc[a][b][c] = (f32x4){0.f, 0.f, 0.f, 0.f};

#pragma unroll
  for (int sh = 0; sh < 9; ++sh) {
    const int kh = sh / 3, kw = sh % 3;
    f16x8 A[KS][4];
#pragma unroll
    for (int ks = 0; ks < KS; ++ks)
#pragma unroll
      for (int og = 0; og < 4; ++og)
        A[ks][og] = *(const f16x8*)(apack + ((((sh * KS + ks) * 4 + og) << 9) + (l << 3)));
#pragma unroll
    for (int rowi = 0; rowi < 2; ++rowi) {
      const char* base = smem + (rl0 + rowi + kh) * ROWB;
#pragma unroll
      for (int pg = 0; pg < PGn; ++pg) {
#pragma unroll
        for (int ks = 0; ks < KS; ++ks) {
          f16x8 B = *(const f16x8*)(base + (px0 + pg * 16 + kw) * PADB + ks * 64 + kg * 16);
#pragma unroll
          for (int og = 0; og < 4; ++og)
            acc[rowi][pg][og] =
                __builtin_amdgcn_mfma_f32_16x16x32_f16(A[ks][og], B, acc[rowi][pg][og], 0, 0, 0);
        }
      }
    }
  }
  constexpr int PH = H / 2, PW = W / 2;
  const int pr = blockIdx.x * (BR / 2) + rp;
#pragma unroll
  for (int pg = 0; pg < PGn; ++pg) {
#pragma unroll
    for (int og = 0; og < 4; ++og) {
      float v[4];
#pragma unroll
      for (int c = 0; c < 4; ++c) {
        float m = fmaxf(acc[0][pg][og][c], acc[1][pg][og][c]);
        v[c] = fmaxf(m, __shfl_xor(m, 1));
      }
      if ((l & 1) == 0) {
        const int pw = (pxb + pg * 16 + lp) >> 1;
        const int oc0 = og * 16 + kg * 4;
        if constexpr (NCHW_OUT) {
          float* o = (float*)hout;
#pragma unroll
          for (int c = 0; c < 4; ++c)
            o[(((size_t)n * 64 + oc0 + c) * PH + pr) * PW + pw] =
                fmaxf(v[c] + bias[oc0 + c], 0.f);
        } else {
          f16x4 pk;
#pragma unroll
          for (int c = 0; c < 4; ++c)
            pk[c] = (f16)fmaxf(v[c] + bias[oc0 + c], 0.f);
          *(f16x4*)((f16*)hout + (((size_t)(n * PH + pr) * PW + pw) * 64 + oc0)) = pk;
        }
      }
    }
  }
}

// ---------------- FC head: 2 batch rows/block, 8-way K-split, 1024 thr --------
// scan collapses: fx = h.(wl2[0]+20*wl2[2]) + bl2[0]+20*bl2[2]
__global__ __launch_bounds__(1024)
void fc_head(const float* __restrict__ h4, const float* __restrict__ wl1,
             const float* __restrict__ bl1, const float* __restrict__ wl2,
             const float* __restrict__ bl2, float* __restrict__ out) {
  __shared__ float rows[2][4096];
  __shared__ float red[8 * 128 * 2];
  __shared__ float red2[2 * 128];
  const int tid = threadIdx.x;
  const int b0 = blockIdx.x * 2;
  {
    const float4* src = (const float4*)(h4 + (size_t)b0 * 4096);
    float4* dst = (float4*)rows;
    for (int t = tid; t < 2048; t += 1024) dst[t] = src[t];
  }
  __syncthreads();

  const int nn = tid & 127;
  const int ks = tid >> 7;                 // 0..7, 512 K each
  const float4* wp = (const float4*)(wl1 + (size_t)nn * 4096 + ks * 512);
  const float4* x0 = (const float4*)(&rows[0][ks * 512]);
  const float4* x1 = (const float4*)(&rows[1][ks * 512]);
  float s0 = 0.f, s1 = 0.f;
#pragma unroll 8
  for (int i = 0; i < 128; ++i) {
    float4 w = wp[i], a = x0[i], b = x1[i];
    s0 = fmaf(w.x, a.x, fmaf(w.y, a.y, fmaf(w.z, a.z, fmaf(w.w, a.w, s0))));
    s1 = fmaf(w.x, b.x, fmaf(w.y, b.y, fmaf(w.z, b.z, fmaf(w.w, b.w, s1))));
  }
  red[(ks * 128 + nn) * 2 + 0] = s0;
  red[(ks * 128 + nn) * 2 + 1] = s1;
  __syncthreads();

  if (tid < 256) {
    const int r = tid >> 7, n2 = tid & 127;
    float h = bl1[n2];
#pragma unroll
    for (int k = 0; k < 8; ++k) h += red[(k * 128 + n2) * 2 + r];
    h = fmaxf(h, 0.f);
    red2[r * 128 + n2] = h * (wl2[n2] + 20.0f * wl2[256 + n2]);
  }
  __syncthreads();
#pragma unroll
  for (int s = 64; s > 0; s >>= 1) {
    if (tid < 2 * s) {
      int r = tid / s, i = tid - r * s;
      red2[r * 128 + i] += red2[r * 128 + i + s];
    }
    __syncthreads();
  }
  if (tid < 2) out[b0 + tid] = red2[tid * 128] + bl2[0] + 20.0f * bl2[2];
}

extern "C" void kernel_launch(void* const* d_in, const int* in_sizes, int n_in,
                              void* d_out, int out_size, void* d_ws, size_t ws_size,
                              hipStream_t stream) {
  const float* x   = (const float*)d_in[0];
  const float* w1  = (const float*)d_in[1];
  const float* b1  = (const float*)d_in[2];
  const float* w2  = (const float*)d_in[3];
  const float* b2  = (const float*)d_in[4];
  const float* w3  = (const float*)d_in[5];
  const float* b3  = (const float*)d_in[6];
  const float* w4  = (const float*)d_in[7];
  const float* b4  = (const float*)d_in[8];
  const float* wl1 = (const float*)d_in[9];
  const float* bl1 = (const float*)d_in[10];
  const float* wl2 = (const float*)d_in[11];
  const float* bl2 = (const float*)d_in[12];
  float* out = (float*)d_out;
  char* ws = (char*)d_ws;

  f16* apack = (f16*)ws;
  f16* h1 = (f16*)(ws + (1u << 20));
  f16* h2 = (f16*)(ws + 68157440u);
  f16* h3 = (f16*)(ws + 101711872u);
  float* h4 = (float*)(ws + 110100480u);

  pack_weights<<<189, 512, 0, stream>>>(w1, w2, w3, w4, apack);
  conv1_mfma<<<dim3(4, 256), 512, 0, stream>>>(x, apack, b1, h1);
  conv_shift<32, 64, 64, 4, 1, 80, 2, false><<<dim3(16, 256), 256, 0, stream>>>(
      h1, apack + 9 * 512, b2, (void*)h2);
  conv_shift<64, 32, 32, 8, 2, 144, 2, false><<<dim3(4, 256), 256, 0, stream>>>(
      h2, apack + 45 * 512, b3, (void*)h3);
  conv_shift<64, 16, 16, 8, 2, 144, 1, true><<<dim3(2, 256), 256, 0, stream>>>(
      h3, apack + 117 * 512, b4, (void*)h4);
  fc_head<<<128, 1024, 0, stream>>>(h4, wl1, bl1, wl2, bl2, out);
}

// Round 11
// 227.367 us; speedup vs baseline: 1.3134x; 1.0833x over previous
//
#include <hip/hip_runtime.h>

// MFMA f16 conv pipeline, round 11.
// Round-10 post-mortem: dbuf conv1 = 117us (neutral vs round-8 one-shot 115):
// 75KB LDS halved residency (2 blk/CU), losing the TLP that pipelining gained.
// Per-pipe audit: VALU ~30us (transpose staging), LDS ~27, HBM ~27, MFMA 16.
// Fix: single 37.4KB buffer (4 blk/CU) + mod-6 ROLLING row window -- adjacent
// tiles share 2 halo rows, so steady state stages only 4 new rows (-33% all
// staging costs). Prefetch loads(t+1) before compute(t) kept.
//
// Layouts (CDNA4):
//   16x16x32: A/B k=(lane>>4)*8+j, m/n=lane&15; D col=lane&15, row=(lane>>4)*4+reg
//   32x32x16: A/B k=(lane>>5)*8+j, m/n=lane&31; D col=lane&31,
//             row=(reg&3)+8*(reg>>2)+4*(lane>>5)

typedef _Float16 f16;
typedef _Float16 f16x8 __attribute__((ext_vector_type(8)));
typedef _Float16 f16x4 __attribute__((ext_vector_type(4)));
typedef float f32x4 __attribute__((ext_vector_type(4)));
typedef float f32x16 __attribute__((ext_vector_type(16)));

// ---------------- weight pre-pack ----------------
// frags (1024B = [lane][j] f16): conv1: 9 (32x32 A, ks=kh*3+kw); conv2: 36 @9;
// conv3: 72 @45; conv4: 72 @117. Total 189.
__global__ __launch_bounds__(512)
void pack_weights(const float* __restrict__ w1, const float* __restrict__ w2,
                  const float* __restrict__ w3, const float* __restrict__ w4,
                  f16* __restrict__ apack) {
  int idx = blockIdx.x * 512 + threadIdx.x;   // 189*512 total
  int frag = idx >> 9;
  int e = idx & 511;
  int lane = e >> 3, j = e & 7;
  float v = 0.f;
  if (frag < 9) {
    int kh = frag / 3, kw = frag % 3;
    int oc = lane & 31;
    int ic = (lane >> 5) * 8 + j;
    if (ic < 12) v = w1[((oc * 12 + ic) * 3 + kh) * 3 + kw];
  } else if (frag < 45) {
    int f = frag - 9;
    int sh = f >> 2, og = f & 3;
    int kh = sh / 3, kw = sh % 3;
    int row16 = lane & 15, kg = lane >> 4;
    int oc = og * 16 + row16;
    int ic = kg * 8 + j;
    v = w2[((oc * 32 + ic) * 3 + kh) * 3 + kw];
  } else {
    const float* w = (frag < 117) ? w3 : w4;
    int f = frag - ((frag < 117) ? 45 : 117);
    int sk = f >> 2, og = f & 3;
    int sh = sk >> 1, ks = sk & 1;
    int kh = sh / 3, kw = sh % 3;
    int row16 = lane & 15, kg = lane >> 4;
    int oc = og * 16 + row16;
    int ic = ks * 32 + kg * 8 + j;
    v = w[((oc * 64 + ic) * 3 + kh) * 3 + kw];
  }
  apack[idx] = (f16)v;
}

// ---------------- conv1: 12ch fp32 NCHW -> 32ch NHWC f16, pool ----------------
// Block: TPB=8 tiles of (4 conv rows x 128 px), 512 threads, SINGLE 6-slot
// rolling LDS window (slot = (ri-R0+1)%6). Steady state stages 4 rows/tile.
// Wave: 2 conv rows x 32 px, 32x32x16 MFMA, k=144 = 9 (kh,kw) x 16ic.
__global__ __launch_bounds__(512)
void conv1_mfma(const float* __restrict__ x, const f16* __restrict__ apack,
                const float* __restrict__ bias, f16* __restrict__ hout) {
  constexpr int W = 128, H = 128;
  constexpr int PADB = 48, ROWB = 130 * PADB;   // 6240 B/row-slot
  constexpr int TPB = 8;
  __shared__ char smem[6 * ROWB];               // 37440 B -> 4 blk/CU
  const int tid = threadIdx.x;
  const int n = blockIdx.y;
  const int R0 = blockIdx.x * (TPB * 4);

  // zero halo columns (px 0 and 129) of all 6 slots (never overwritten)
  if (tid < 36) {
    int slot = tid / 6, r = tid % 6;
    int px = (r >= 3) ? 129 : 0;
    int ch = r % 3;
    *(float4*)(smem + slot * ROWB + px * PADB + ch * 16) =
        make_float4(0.f, 0.f, 0.f, 0.f);
  }

  // staging roles: group g (=tid>>4) owns px chunk g (4 px); l16 = channel.
  const int g = tid >> 4;
  const int l16 = tid & 15;
  const int Q = l16 >> 2, q = l16 & 3;          // quad, lane-in-quad

  auto load_row = [&](int ri) -> float4 {
    float4 v = make_float4(0.f, 0.f, 0.f, 0.f);
    if (l16 < 12 && ri >= 0 && ri < H)
      v = *(const float4*)(x + ((size_t)(n * 12 + l16) * H + ri) * W + g * 4);
    return v;
  };
  auto xpose_write = [&](float4 av, int slot) {
    float4 t1, t2;
    {
      float sx = __shfl_xor(av.x, 1), sy = __shfl_xor(av.y, 1);
      float sz = __shfl_xor(av.z, 1), sw = __shfl_xor(av.w, 1);
      bool odd = q & 1;
      t1.x = odd ? sy : av.x;  t1.y = odd ? av.y : sx;
      t1.z = odd ? sw : av.z;  t1.w = odd ? av.w : sz;
    }
    {
      float sx = __shfl_xor(t1.x, 2), sy = __shfl_xor(t1.y, 2);
      float sz = __shfl_xor(t1.z, 2), sw = __shfl_xor(t1.w, 2);
      bool hi2 = q & 2;
      t2.x = hi2 ? sz : t1.x;  t2.y = hi2 ? sw : t1.y;
      t2.z = hi2 ? t1.z : sx;  t2.w = hi2 ? t1.w : sy;
    }
    f16x4 h = { (f16)t2.x, (f16)t2.y, (f16)t2.z, (f16)t2.w };
    *(f16x4*)(smem + slot * ROWB + (g * 4 + q + 1) * PADB + Q * 8) = h;
  };

  // compute-role indices
  const int wv = tid >> 6, l = tid & 63;
  const int rp = wv >> 2;                // pooled row within tile (0..1)
  const int pxb = (wv & 3) * 32;
  const int rl0 = rp * 2;
  const int ln = l & 31;                 // px lane (n of MFMA)
  const int hi = l >> 5;                 // k-half / D row offset

  f16x8 A[9];
#pragma unroll
  for (int ks = 0; ks < 9; ++ks)
    A[ks] = *(const f16x8*)(apack + ((ks << 9) + (l << 3)));

  float4 a[6];
  // prologue: stage rows R0-1 .. R0+4 into slots 0..5
#pragma unroll
  for (int i = 0; i < 6; ++i) a[i] = load_row(R0 - 1 + i);
#pragma unroll
  for (int i = 0; i < 6; ++i) xpose_write(a[i], i);
  __syncthreads();

  int s0 = 0;                            // slot of row R0+4t-1
  for (int t = 0; t < TPB; ++t) {
    if (t + 1 < TPB) {                   // issue next-tile loads early
#pragma unroll
      for (int i = 0; i < 4; ++i) a[i] = load_row(R0 + 4 * t + 5 + i);
    }
    // compute tile t: reads slots s0..s0+5 (mod 6)
    f32x16 acc0 = (f32x16)0.f, acc1 = (f32x16)0.f;
#pragma unroll
    for (int ks = 0; ks < 9; ++ks) {
      const int kh = ks / 3, kw = ks % 3;
      int sl0 = s0 + rl0 + kh;     if (sl0 >= 6) sl0 -= 6;
      int sl1 = s0 + rl0 + 1 + kh; if (sl1 >= 6) sl1 -= 6;
      const char* bcol = smem + (pxb + ln + kw) * PADB + hi * 16;
      f16x8 B0 = *(const f16x8*)(bcol + sl0 * ROWB);
      acc0 = __builtin_amdgcn_mfma_f32_32x32x16_f16(A[ks], B0, acc0, 0, 0, 0);
      f16x8 B1 = *(const f16x8*)(bcol + sl1 * ROWB);
      acc1 = __builtin_amdgcn_mfma_f32_32x32x16_f16(A[ks], B1, acc1, 0, 0, 0);
    }
    // epilogue: pool 2x2, bias, relu, NHWC f16 store (OC=32)
    {
      const int pr = (R0 >> 1) + 2 * t + rp;
#pragma unroll
      for (int gg = 0; gg < 4; ++gg) {
        float v[4];
#pragma unroll
        for (int c = 0; c < 4; ++c) {
          float m = fmaxf(acc0[gg * 4 + c], acc1[gg * 4 + c]);
          v[c] = fmaxf(m, __shfl_xor(m, 1));
        }
        if ((l & 1) == 0) {
          const int pw = (pxb + ln) >> 1;
          const int oc0 = gg * 8 + hi * 4;
          f16x4 pk;
#pragma unroll
          for (int c = 0; c < 4; ++c)
            pk[c] = (f16)fmaxf(v[c] + bias[oc0 + c], 0.f);
          *(f16x4*)(hout + (((size_t)(n * 64 + pr) * 64 + pw) * 32 + oc0)) = pk;
        }
      }
    }
    __syncthreads();
    if (t + 1 < TPB) {                   // overwrite slots s0..s0+3 (mod 6)
#pragma unroll
      for (int i = 0; i < 4; ++i) {
        int sl = s0 + i; if (sl >= 6) sl -= 6;
        xpose_write(a[i], sl);
      }
      __syncthreads();
    }
    s0 += 4; if (s0 >= 6) s0 -= 6;
  }
}

// ---------------- conv2/3/4: NHWC f16 -> NHWC f16 (or NCHW f32), pool ----------
template<int C, int W, int H, int BR, int KS, int PADB, int PGn, bool NCHW_OUT>
__global__ __launch_bounds__(256)
void conv_shift(const f16* __restrict__ hin, const f16* __restrict__ apack,
                const float* __restrict__ bias, void* __restrict__ hout) {
  constexpr int SR = BR + 2;
  constexpr int ROWB = (W + 2) * PADB;
  __shared__ char smem[SR * ROWB];
  const int tid = threadIdx.x;
  const int n = blockIdx.y;
  const int r0 = blockIdx.x * BR;
  constexpr int CPC = C / 8;
  constexpr int TOTC = SR * (W + 2) * CPC;
  constexpr int NITER = (TOTC + 255) / 256;
  {
    float4 stg[NITER];
#pragma unroll
    for (int it = 0; it < NITER; ++it) {     // phase 1: issue all loads
      const int t = tid + it * 256;
      float4 v = make_float4(0.f, 0.f, 0.f, 0.f);
      if (t < TOTC) {
        int sr = t / ((W + 2) * CPC);
        int rem = t - sr * ((W + 2) * CPC);
        int px = rem / CPC;
        int kc = rem - px * CPC;
        int ri = r0 + sr - 1;
        int gx = px - 1;
        if (ri >= 0 && ri < H && gx >= 0 && gx < W)
          v = *(const float4*)(hin + (((size_t)(n * H + ri) * W + gx) * C + kc * 8));
      }
      stg[it] = v;
    }
#pragma unroll
    for (int it = 0; it < NITER; ++it) {     // phase 2: write to LDS
      const int t = tid + it * 256;
      if (t < TOTC) {
        int sr = t / ((W + 2) * CPC);
        int rem = t - sr * ((W + 2) * CPC);
        int px = rem / CPC;
        int kc = rem - px * CPC;
        *(float4*)(smem + sr * ROWB + px * PADB + kc * 16) = stg[it];
      }
    }
  }
  __syncthreads();

  const int wv = tid >> 6, l = tid & 63;
  constexpr int WPP = W / (16 * PGn);
  const int rp = wv / WPP;
  const int pxb = (wv % WPP) * 16 * PGn;
  const int rl0 = rp * 2;
  const int lp = l & 15, kg = l >> 4;
  const int px0 = pxb + lp;

  f32x4 acc[2][PGn][4];
#pragma unroll
  for (int a = 0; a < 2; ++a)
#pragma unroll
    for (int b = 0; b < PGn; ++b)
#pragma unroll
      for (int c = 0; c < 4; ++c)
        acc[a][b][c] = (f32x4){0.f, 0.f, 0.f, 0.f};

#pragma unroll
  for (int sh = 0; sh < 9; ++sh) {
    const int kh = sh / 3, kw = sh % 3;
    f16x8 A[KS][4];
#pragma unroll
    for (int ks = 0; ks < KS; ++ks)
#pragma unroll
      for (int og = 0; og < 4; ++og)
        A[ks][og] = *(const f16x8*)(apack + ((((sh * KS + ks) * 4 + og) << 9) + (l << 3)));
#pragma unroll
    for (int rowi = 0; rowi < 2; ++rowi) {
      const char* base = smem + (rl0 + rowi + kh) * ROWB;
#pragma unroll
      for (int pg = 0; pg < PGn; ++pg) {
#pragma unroll
        for (int ks = 0; ks < KS; ++ks) {
          f16x8 B = *(const f16x8*)(base + (px0 + pg * 16 + kw) * PADB + ks * 64 + kg * 16);
#pragma unroll
          for (int og = 0; og < 4; ++og)
            acc[rowi][pg][og] =
                __builtin_amdgcn_mfma_f32_16x16x32_f16(A[ks][og], B, acc[rowi][pg][og], 0, 0, 0);
        }
      }
    }
  }
  constexpr int PH = H / 2, PW = W / 2;
  const int pr = blockIdx.x * (BR / 2) + rp;
#pragma unroll
  for (int pg = 0; pg < PGn; ++pg) {
#pragma unroll
    for (int og = 0; og < 4; ++og) {
      float v[4];
#pragma unroll
      for (int c = 0; c < 4; ++c) {
        float m = fmaxf(acc[0][pg][og][c], acc[1][pg][og][c]);
        v[c] = fmaxf(m, __shfl_xor(m, 1));
      }
      if ((l & 1) == 0) {
        const int pw = (pxb + pg * 16 + lp) >> 1;
        const int oc0 = og * 16 + kg * 4;
        if constexpr (NCHW_OUT) {
          float* o = (float*)hout;
#pragma unroll
          for (int c = 0; c < 4; ++c)
            o[(((size_t)n * 64 + oc0 + c) * PH + pr) * PW + pw] =
                fmaxf(v[c] + bias[oc0 + c], 0.f);
        } else {
          f16x4 pk;
#pragma unroll
          for (int c = 0; c < 4; ++c)
            pk[c] = (f16)fmaxf(v[c] + bias[oc0 + c], 0.f);
          *(f16x4*)((f16*)hout + (((size_t)(n * PH + pr) * PW + pw) * 64 + oc0)) = pk;
        }
      }
    }
  }
}

// ---------------- FC head: 2 batch rows/block, 8-way K-split, 1024 thr --------
// scan collapses: fx = h.(wl2[0]+20*wl2[2]) + bl2[0]+20*bl2[2]
__global__ __launch_bounds__(1024)
void fc_head(const float* __restrict__ h4, const float* __restrict__ wl1,
             const float* __restrict__ bl1, const float* __restrict__ wl2,
             const float* __restrict__ bl2, float* __restrict__ out) {
  __shared__ float rows[2][4096];
  __shared__ float red[8 * 128 * 2];
  __shared__ float red2[2 * 128];
  const int tid = threadIdx.x;
  const int b0 = blockIdx.x * 2;
  {
    const float4* src = (const float4*)(h4 + (size_t)b0 * 4096);
    float4* dst = (float4*)rows;
    for (int t = tid; t < 2048; t += 1024) dst[t] = src[t];
  }
  __syncthreads();

  const int nn = tid & 127;
  const int ks = tid >> 7;                 // 0..7, 512 K each
  const float4* wp = (const float4*)(wl1 + (size_t)nn * 4096 + ks * 512);
  const float4* x0 = (const float4*)(&rows[0][ks * 512]);
  const float4* x1 = (const float4*)(&rows[1][ks * 512]);
  float s0 = 0.f, s1 = 0.f;
#pragma unroll 8
  for (int i = 0; i < 128; ++i) {
    float4 w = wp[i], a = x0[i], b = x1[i];
    s0 = fmaf(w.x, a.x, fmaf(w.y, a.y, fmaf(w.z, a.z, fmaf(w.w, a.w, s0))));
    s1 = fmaf(w.x, b.x, fmaf(w.y, b.y, fmaf(w.z, b.z, fmaf(w.w, b.w, s1))));
  }
  red[(ks * 128 + nn) * 2 + 0] = s0;
  red[(ks * 128 + nn) * 2 + 1] = s1;
  __syncthreads();

  if (tid < 256) {
    const int r = tid >> 7, n2 = tid & 127;
    float h = bl1[n2];
#pragma unroll
    for (int k = 0; k < 8; ++k) h += red[(k * 128 + n2) * 2 + r];
    h = fmaxf(h, 0.f);
    red2[r * 128 + n2] = h * (wl2[n2] + 20.0f * wl2[256 + n2]);
  }
  __syncthreads();
#pragma unroll
  for (int s = 64; s > 0; s >>= 1) {
    if (tid < 2 * s) {
      int r = tid / s, i = tid - r * s;
      red2[r * 128 + i] += red2[r * 128 + i + s];
    }
    __syncthreads();
  }
  if (tid < 2) out[b0 + tid] = red2[tid * 128] + bl2[0] + 20.0f * bl2[2];
}

extern "C" void kernel_launch(void* const* d_in, const int* in_sizes, int n_in,
                              void* d_out, int out_size, void* d_ws, size_t ws_size,
                              hipStream_t stream) {
  const float* x   = (const float*)d_in[0];
  const float* w1  = (const float*)d_in[1];
  const float* b1  = (const float*)d_in[2];
  const float* w2  = (const float*)d_in[3];
  const float* b2  = (const float*)d_in[4];
  const float* w3  = (const float*)d_in[5];
  const float* b3  = (const float*)d_in[6];
  const float* w4  = (const float*)d_in[7];
  const float* b4  = (const float*)d_in[8];
  const float* wl1 = (const float*)d_in[9];
  const float* bl1 = (const float*)d_in[10];
  const float* wl2 = (const float*)d_in[11];
  const float* bl2 = (const float*)d_in[12];
  float* out = (float*)d_out;
  char* ws = (char*)d_ws;

  f16* apack = (f16*)ws;
  f16* h1 = (f16*)(ws + (1u << 20));
  f16* h2 = (f16*)(ws + 68157440u);
  f16* h3 = (f16*)(ws + 101711872u);
  float* h4 = (float*)(ws + 110100480u);

  pack_weights<<<189, 512, 0, stream>>>(w1, w2, w3, w4, apack);
  conv1_mfma<<<dim3(4, 256), 512, 0, stream>>>(x, apack, b1, h1);
  conv_shift<32, 64, 64, 4, 1, 80, 2, false><<<dim3(16, 256), 256, 0, stream>>>(
      h1, apack + 9 * 512, b2, (void*)h2);
  conv_shift<64, 32, 32, 8, 2, 144, 2, false><<<dim3(4, 256), 256, 0, stream>>>(
      h2, apack + 45 * 512, b3, (void*)h3);
  conv_shift<64, 16, 16, 8, 2, 144, 1, true><<<dim3(2, 256), 256, 0, stream>>>(
      h3, apack + 117 * 512, b4, (void*)h4);
  fc_head<<<128, 1024, 0, stream>>>(h4, wl1, bl1, wl2, bl2, out);
}